// Round 1
// baseline (1488.055 us; speedup 1.0000x reference)
//
#include <hip/hip_runtime.h>
#include <stdint.h>

#define B_ 512
#define L_ 48
#define D_ 256

typedef __attribute__((ext_vector_type(8))) short bf16x8;
typedef __attribute__((ext_vector_type(4))) short bf16x4;
typedef __attribute__((ext_vector_type(4))) float f32x4;

__device__ __forceinline__ short f2bf(float f) {
    union { float f; unsigned u; } v; v.f = f;
    unsigned u = v.u;
    unsigned r = (u + 0x7FFFu + ((u >> 16) & 1u)) >> 16;
    return (short)r;
}
__device__ __forceinline__ float bf2f(short s) {
    union { unsigned u; float f; } v; v.u = ((unsigned)(unsigned short)s) << 16;
    return v.f;
}

// ---------------- weight prep: fp32 -> bf16, concat [w_hh;w_h] ----------------
__global__ __launch_bounds__(256) void k_prep(const float* __restrict__ w_hh,
                                              const float* __restrict__ w_h,
                                              const float* __restrict__ w_ih,
                                              short* __restrict__ W1,
                                              short* __restrict__ W2) {
    int t = blockIdx.x * 256 + threadIdx.x;
    const int N1 = 768 * 256;        // w_hh part
    const int N1b = 816 * 256;       // + w_h part
    if (t < N1) {
        W1[t] = f2bf(w_hh[t]);
    } else if (t < N1b) {
        W1[t] = f2bf(w_h[t - N1]);
    } else {
        int u = t - N1b;
        if (u < 768 * 256) W2[u] = f2bf(w_ih[u]);
    }
}

// ---------------- embedding GEMM: x = relu(x1@we1^T+b1) + relu(x2@we2^T+b2) ----
__device__ __forceinline__ void gemm_pass(const float* __restrict__ X,
                                          const float* __restrict__ W,
                                          short (*sA)[40], short (*sB)[40],
                                          int m0, int n0, int srow, int sseg,
                                          int mf, int nf, int row16, int kg,
                                          f32x4 (&acc)[2][4]) {
    for (int k0 = 0; k0 < 512; k0 += 32) {
        __syncthreads();
        {
            const float* src = X + (size_t)(m0 + srow) * 512 + k0 + sseg * 8;
            float4 p0 = *(const float4*)(src);
            float4 p1 = *(const float4*)(src + 4);
            bf16x8 v;
            v[0] = f2bf(p0.x); v[1] = f2bf(p0.y); v[2] = f2bf(p0.z); v[3] = f2bf(p0.w);
            v[4] = f2bf(p1.x); v[5] = f2bf(p1.y); v[6] = f2bf(p1.z); v[7] = f2bf(p1.w);
            *(bf16x8*)&sA[srow][sseg * 8] = v;
        }
        {
            const float* src = W + (size_t)(n0 + srow) * 512 + k0 + sseg * 8;
            float4 p0 = *(const float4*)(src);
            float4 p1 = *(const float4*)(src + 4);
            bf16x8 v;
            v[0] = f2bf(p0.x); v[1] = f2bf(p0.y); v[2] = f2bf(p0.z); v[3] = f2bf(p0.w);
            v[4] = f2bf(p1.x); v[5] = f2bf(p1.y); v[6] = f2bf(p1.z); v[7] = f2bf(p1.w);
            *(bf16x8*)&sB[srow][sseg * 8] = v;
        }
        __syncthreads();
        bf16x8 a0 = *(bf16x8*)&sA[(mf + 0) * 16 + row16][kg * 8];
        bf16x8 a1 = *(bf16x8*)&sA[(mf + 1) * 16 + row16][kg * 8];
        #pragma unroll
        for (int j = 0; j < 4; ++j) {
            bf16x8 bv = *(bf16x8*)&sB[(nf + j) * 16 + row16][kg * 8];
            acc[0][j] = __builtin_amdgcn_mfma_f32_16x16x32_bf16(a0, bv, acc[0][j], 0, 0, 0);
            acc[1][j] = __builtin_amdgcn_mfma_f32_16x16x32_bf16(a1, bv, acc[1][j], 0, 0, 0);
        }
    }
}

__global__ __launch_bounds__(512) void k_embed(const float* __restrict__ x1,
                                               const float* __restrict__ x2,
                                               const float* __restrict__ w_e1,
                                               const float* __restrict__ b_e1,
                                               const float* __restrict__ w_e2,
                                               const float* __restrict__ b_e2,
                                               short* __restrict__ xb) {
    __shared__ short sA[128][40];
    __shared__ short sB[128][40];
    int bid = blockIdx.x;
    int mt = bid >> 1, nt = bid & 1;
    int m0 = mt * 128, n0 = nt * 128;
    int tid = threadIdx.x;
    int lane = tid & 63, w = tid >> 6;
    int mf = (w & 3) * 2;
    int nf = (w >> 2) * 4;
    int row16 = lane & 15, kg = lane >> 4;
    int srow = tid >> 2, sseg = tid & 3;

    f32x4 acc[2][4], keep[2][4];
    #pragma unroll
    for (int a = 0; a < 2; ++a)
        #pragma unroll
        for (int j = 0; j < 4; ++j) { acc[a][j] = {0.f, 0.f, 0.f, 0.f}; }

    gemm_pass(x1, w_e1, sA, sB, m0, n0, srow, sseg, mf, nf, row16, kg, acc);
    #pragma unroll
    for (int a = 0; a < 2; ++a)
        #pragma unroll
        for (int j = 0; j < 4; ++j) { keep[a][j] = acc[a][j]; acc[a][j] = {0.f, 0.f, 0.f, 0.f}; }
    gemm_pass(x2, w_e2, sA, sB, m0, n0, srow, sseg, mf, nf, row16, kg, acc);

    #pragma unroll
    for (int a = 0; a < 2; ++a) {
        int mbase = m0 + (mf + a) * 16 + kg * 4;
        #pragma unroll
        for (int j = 0; j < 4; ++j) {
            int n = n0 + (nf + j) * 16 + row16;
            float be1 = b_e1[n], be2 = b_e2[n];
            #pragma unroll
            for (int e = 0; e < 4; ++e) {
                float v1 = fmaxf(keep[a][j][e] + be1, 0.f);
                float v2 = fmaxf(acc[a][j][e] + be2, 0.f);
                xb[(size_t)(mbase + e) * 256 + n] = f2bf(v1 + v2);
            }
        }
    }
}

// ------------- aux: exact fp32 channel-0 of x2e (for cond), and xw = x . w_x ----
__global__ __launch_bounds__(256) void k_aux(const float* __restrict__ x2,
                                             const float* __restrict__ w_e2,
                                             const float* __restrict__ b_e2,
                                             const short* __restrict__ xb,
                                             const float* __restrict__ w_x,
                                             float* __restrict__ c0,
                                             float* __restrict__ xw) {
    int w = threadIdx.x >> 6, lane = threadIdx.x & 63;
    int m = blockIdx.x * 4 + w;
    const float* xr = x2 + (size_t)m * 512 + lane * 8;
    const float* wr = w_e2 + lane * 8;
    float s = 0.f;
    #pragma unroll
    for (int q = 0; q < 8; ++q) s += xr[q] * wr[q];
    #pragma unroll
    for (int o = 32; o; o >>= 1) s += __shfl_xor(s, o);
    float pre = s + b_e2[0];

    float t = 0.f;
    if (lane < 32) {
        const short* xbr = xb + (size_t)m * 256 + lane * 8;
        #pragma unroll
        for (int q = 0; q < 8; ++q) t += bf2f(xbr[q]) * w_x[lane * 8 + q];
    }
    #pragma unroll
    for (int o = 32; o; o >>= 1) t += __shfl_xor(t, o);
    if (lane == 0) { c0[m] = fmaxf(pre, 0.f); xw[m] = t; }
}

// ------------- aux2: cond bitmasks per batch + se = s@w_s^T + b_s --------------
__global__ __launch_bounds__(256) void k_aux2(const float* __restrict__ c0,
                                              const float* __restrict__ s_in,
                                              const float* __restrict__ w_s,
                                              const float* __restrict__ b_s,
                                              unsigned long long* __restrict__ condbits,
                                              float* __restrict__ se) {
    __shared__ float sS[64];
    int b = blockIdx.x;
    int t = threadIdx.x;
    if (t < 64) sS[t] = s_in[b * 64 + t];
    __syncthreads();
    float acc = b_s[t];
    const float* wr = w_s + t * 64;
    #pragma unroll 8
    for (int k = 0; k < 64; ++k) acc += sS[k] * wr[k];
    se[(size_t)b * 256 + t] = acc;
    if (t == 0) {
        unsigned long long bits = 0;
        bool run = true;
        const float* cr = c0 + (size_t)b * 48;
        for (int i = 0; i < 48; ++i) {
            if (run) bits |= (1ull << i);
            run = run && (cr[i] == 0.0f);
        }
        condbits[b] = bits;
    }
}

// ---------------- persistent scan: 32 blocks x 16 batches, 48 steps ------------
__global__ __launch_bounds__(512) void k_scan(const short* __restrict__ W1,
                                              const short* __restrict__ W2,
                                              const float* __restrict__ b_hh,
                                              const float* __restrict__ b_h,
                                              const float* __restrict__ b_ih,
                                              const short* __restrict__ xb,
                                              const float* __restrict__ xw,
                                              const unsigned long long* __restrict__ condbits,
                                              const float* __restrict__ se,
                                              const float* __restrict__ w_out,
                                              const float* __restrict__ b_out,
                                              float* __restrict__ out) {
    __shared__ float lH[16][256];
    __shared__ short lA[16][264];   // bf16 operand (h, then ctx), padded
    __shared__ float lG[16][820];   // gh(768) | hW(48), padded to 820
    __shared__ float lN[16][260];   // i_n, padded
    __shared__ float lT[16][48];    // softmax a
    __shared__ float lXW[16][48];
    __shared__ unsigned long long lC[16];

    int tid = threadIdx.x;
    int w = tid >> 6, lane = tid & 63;
    int row16 = lane & 15, kg = lane >> 4;
    int b0 = blockIdx.x * 16;

    for (int t = tid; t < 16 * 48; t += 512) {
        int m = t / 48, j = t % 48;
        lXW[m][j] = xw[(size_t)(b0 + m) * 48 + j];
    }
    if (tid < 16) lC[tid] = condbits[b0 + tid];
    for (int t = tid; t < 16 * 256; t += 512) {
        int m = t >> 8, d = t & 255;
        lH[m][d] = 0.f;
        lA[m][d] = 0;
    }
    __syncthreads();

    for (int i = 0; i < 48; ++i) {
        // Phase A: [gh | hW] = h @ [w_hh | w_h]^T + [b_hh | b_h]
        for (int t = w; t < 51; t += 8) {
            f32x4 acc = {0.f, 0.f, 0.f, 0.f};
            const short* wp = W1 + ((size_t)(t * 16 + row16) * 256 + kg * 8);
            const short* ap = &lA[row16][kg * 8];
            #pragma unroll
            for (int s = 0; s < 8; ++s) {
                bf16x8 av = *(const bf16x8*)(ap + s * 32);
                bf16x8 bv = *(const bf16x8*)(wp + s * 32);
                acc = __builtin_amdgcn_mfma_f32_16x16x32_bf16(av, bv, acc, 0, 0, 0);
            }
            int n = t * 16 + row16;
            float bias = (n < 768) ? b_hh[n] : b_h[n - 768];
            #pragma unroll
            for (int e = 0; e < 4; ++e) lG[kg * 4 + e][n] = acc[e] + bias;
        }
        __syncthreads();

        // Phase B1: softmax over all 48 positions
        #pragma unroll
        for (int rep = 0; rep < 2; ++rep) {
            int m = w * 2 + rep;
            float val = -3.0e38f;
            if (lane < 48) {
                val = lG[m][768 + lane];
                bool cb = (lC[m] >> i) & 1ull;
                if (lane == i) val += lXW[m][i];
                else if (cb && lane < i) val += lXW[m][lane];
            }
            float mx = val;
            #pragma unroll
            for (int o = 32; o; o >>= 1) mx = fmaxf(mx, __shfl_xor(mx, o));
            float ex = (lane < 48) ? __expf(val - mx) : 0.f;
            float sm = ex;
            #pragma unroll
            for (int o = 32; o; o >>= 1) sm += __shfl_xor(sm, o);
            if (lane < 48) lT[m][lane] = ex / sm;
        }
        __syncthreads();

        // Phase B2: ctx = sum_{j<=i} a_j * x[b,j,:]  (fp32 accum, bf16 out)
        #pragma unroll
        for (int rep = 0; rep < 2; ++rep) {
            int m = w * 2 + rep;
            const short* xr = xb + (size_t)(b0 + m) * 48 * 256 + lane * 4;
            float c0v = 0.f, c1v = 0.f, c2v = 0.f, c3v = 0.f;
            #pragma unroll 4
            for (int j = 0; j <= i; ++j) {
                float aj = lT[m][j];
                bf16x4 v = *(const bf16x4*)(xr + j * 256);
                c0v += aj * bf2f(v.x);
                c1v += aj * bf2f(v.y);
                c2v += aj * bf2f(v.z);
                c3v += aj * bf2f(v.w);
            }
            bf16x4 o;
            o.x = f2bf(c0v); o.y = f2bf(c1v); o.z = f2bf(c2v); o.w = f2bf(c3v);
            *(bf16x4*)&lA[m][lane * 4] = o;
        }
        __syncthreads();

        // Phase C: gi = ctx @ w_ih^T + b_ih ; r/z summed into lG, i_n -> lN
        for (int t = w; t < 48; t += 8) {
            f32x4 acc = {0.f, 0.f, 0.f, 0.f};
            const short* wp = W2 + ((size_t)(t * 16 + row16) * 256 + kg * 8);
            const short* ap = &lA[row16][kg * 8];
            #pragma unroll
            for (int s = 0; s < 8; ++s) {
                bf16x8 av = *(const bf16x8*)(ap + s * 32);
                bf16x8 bv = *(const bf16x8*)(wp + s * 32);
                acc = __builtin_amdgcn_mfma_f32_16x16x32_bf16(av, bv, acc, 0, 0, 0);
            }
            int n = t * 16 + row16;
            float bias = b_ih[n];
            if (n < 512) {
                #pragma unroll
                for (int e = 0; e < 4; ++e) lG[kg * 4 + e][n] += acc[e] + bias;
            } else {
                #pragma unroll
                for (int e = 0; e < 4; ++e) lN[kg * 4 + e][n - 512] = acc[e] + bias;
            }
        }
        __syncthreads();

        // Phase D: GRU update
        {
            int m = tid >> 5, dbase = (tid & 31) * 8;
            bf16x8 packed;
            #pragma unroll
            for (int q = 0; q < 8; ++q) {
                int d = dbase + q;
                float r = 1.f / (1.f + __expf(-lG[m][d]));
                float z = 1.f / (1.f + __expf(-lG[m][256 + d]));
                float nn = tanhf(lN[m][d] + r * lG[m][512 + d]);
                float hp = (1.f - z) * nn + z * lH[m][d];
                lH[m][d] = hp;
                packed[q] = f2bf(hp);
            }
            *(bf16x8*)&lA[m][dbase] = packed;
        }
        __syncthreads();
    }

    // epilogue: y = sigmoid((hF + se) . w_out + b_out)
    #pragma unroll
    for (int rep = 0; rep < 2; ++rep) {
        int m = w * 2 + rep;
        int b = b0 + m;
        int d = lane * 4;
        float acc = 0.f;
        #pragma unroll
        for (int q = 0; q < 4; ++q)
            acc += (lH[m][d + q] + se[(size_t)b * 256 + d + q]) * w_out[d + q];
        #pragma unroll
        for (int o = 32; o; o >>= 1) acc += __shfl_xor(acc, o);
        if (lane == 0) out[b] = 1.f / (1.f + __expf(-(acc + b_out[0])));
    }
}

extern "C" void kernel_launch(void* const* d_in, const int* in_sizes, int n_in,
                              void* d_out, int out_size, void* d_ws, size_t ws_size,
                              hipStream_t stream) {
    const float* x1   = (const float*)d_in[0];
    const float* x2   = (const float*)d_in[1];
    const float* s    = (const float*)d_in[2];
    const float* w_e1 = (const float*)d_in[3];
    const float* b_e1 = (const float*)d_in[4];
    const float* w_e2 = (const float*)d_in[5];
    const float* b_e2 = (const float*)d_in[6];
    const float* w_s  = (const float*)d_in[7];
    const float* b_s  = (const float*)d_in[8];
    const float* w_x  = (const float*)d_in[9];
    const float* w_h  = (const float*)d_in[10];
    const float* b_h  = (const float*)d_in[11];
    const float* w_ih = (const float*)d_in[12];
    const float* w_hh = (const float*)d_in[13];
    const float* b_ih = (const float*)d_in[14];
    const float* b_hh = (const float*)d_in[15];
    const float* w_out = (const float*)d_in[16];
    const float* b_out = (const float*)d_in[17];
    float* out = (float*)d_out;

    char* ws = (char*)d_ws;
    size_t off = 0;
    auto alloc = [&](size_t bytes) -> void* {
        void* p = ws + off;
        off = (off + bytes + 255) & ~(size_t)255;
        return p;
    };
    short* xb = (short*)alloc((size_t)B_ * L_ * D_ * 2);
    short* W1 = (short*)alloc(816 * 256 * 2);
    short* W2 = (short*)alloc(768 * 256 * 2);
    float* c0 = (float*)alloc((size_t)B_ * L_ * 4);
    float* xw = (float*)alloc((size_t)B_ * L_ * 4);
    unsigned long long* cb = (unsigned long long*)alloc(B_ * 8);
    float* se = (float*)alloc((size_t)B_ * D_ * 4);

    hipLaunchKernelGGL(k_prep, dim3((816 * 256 + 768 * 256) / 256), dim3(256), 0, stream,
                       w_hh, w_h, w_ih, W1, W2);
    hipLaunchKernelGGL(k_embed, dim3(384), dim3(512), 0, stream,
                       x1, x2, w_e1, b_e1, w_e2, b_e2, xb);
    hipLaunchKernelGGL(k_aux, dim3(6144), dim3(256), 0, stream,
                       x2, w_e2, b_e2, xb, w_x, c0, xw);
    hipLaunchKernelGGL(k_aux2, dim3(512), dim3(256), 0, stream,
                       c0, s, w_s, b_s, cb, se);
    hipLaunchKernelGGL(k_scan, dim3(32), dim3(512), 0, stream,
                       W1, W2, b_hh, b_h, b_ih, xb, xw, cb, se, w_out, b_out, out);
}